// Round 5
// baseline (531.241 us; speedup 1.0000x reference)
//
#include <hip/hip_runtime.h>
#include <stdint.h>

#define STENCIL 24
#define EPS_F 1e-4f
#define BLK 256
#define NXCD 8

#define NODE_N 262144                       // nodes per batch (fixed problem size)
#define BIN_NODES 2048                      // nodes per bin (8 KB LDS accumulator)
#define LBINS 128                           // bins per batch
#define NBINS 256                           // 2 batches * 128
#define BIN_CAP_G 49152                     // per-bin pair capacity: mean 47722, +6.5 sigma

#define S_THREADS 512
#define S_EPT 16
#define EDGES_PER_BLOCK (S_THREADS * S_EPT) // 8192

typedef int   i32x2 __attribute__((ext_vector_type(2)));

// nontemporal scalar load (no-allocate hint: keep streams out of L2 so the
// small gather targets u/v stay resident)
template <typename T>
static __device__ __forceinline__ T ntload(const T* p) {
    return __builtin_nontemporal_load(p);
}

// ---- XCD id (fallback path only), verified gfx950 (learn_hip m09)
static __device__ __forceinline__ int get_xcc_id() {
    int x;
    asm volatile("s_getreg_b32 %0, hwreg(HW_REG_XCC_ID)" : "=s"(x));
    return x & (NXCD - 1);
}

__device__ __forceinline__ float wave_reduce_f32(float v) {
    #pragma unroll
    for (int off = 32; off > 0; off >>= 1)
        v += __shfl_down(v, off, 64);
    return v;
}

__device__ __forceinline__ float block_reduce_f32(float v) {
    __shared__ float sw[BLK / 64];
    float s = wave_reduce_f32(v);
    if ((threadIdx.x & 63) == 0) sw[threadIdx.x >> 6] = s;
    __syncthreads();
    float r = 0.f;
    if (threadIdx.x == 0) {
        #pragma unroll
        for (int k = 0; k < BLK / 64; ++k) r += sw[k];
    }
    return r;
}

// K1: per-block partials of sum|A| and sum(mask)
__global__ void k_reduce(const float* __restrict__ Ad, const float* __restrict__ Ao,
                         const float* __restrict__ mask, long long BN,
                         float* __restrict__ pn, float* __restrict__ pa) {
    long long total = BN * STENCIL;
    long long stride = (long long)gridDim.x * blockDim.x;
    float s = 0.f, act = 0.f;
    for (long long t = (long long)blockIdx.x * blockDim.x + threadIdx.x; t < total; t += stride) {
        s += fabsf(ntload(Ao + t));
        if (t < BN) { s += fabsf(ntload(Ad + t)); act += ntload(mask + t); }
    }
    float bs = block_reduce_f32(s);
    if (threadIdx.x == 0) pn[blockIdx.x] = bs;
    __syncthreads();
    float ba = block_reduce_f32(act);
    if (threadIdx.x == 0) pa[blockIdx.x] = ba;
}

// K2: scal[0]=norm_A, scal[1]=active
__global__ void k_scal(const float* __restrict__ pn, const float* __restrict__ pa,
                       int nblk, double* __restrict__ scal) {
    float sn = 0.f, sa = 0.f;
    for (int t = threadIdx.x; t < nblk; t += blockDim.x) { sn += pn[t]; sa += pa[t]; }
    float bn_ = block_reduce_f32(sn);
    __shared__ double dn;
    if (threadIdx.x == 0) dn = (double)bn_;
    __syncthreads();
    float ba = block_reduce_f32(sa);
    if (threadIdx.x == 0) {
        double act = (double)ba;
        scal[0] = dn / (act * 25.0 + 1e-6);
        scal[1] = act;
    }
}

// K3: block counting-sort of edges by target bin; dense pair write-out.
// STRIDED edge mapping: edge t = blockStart + e*S_THREADS + tid, so every
// global load has lane-consecutive addresses (~2-3 L1 segments/instr).
// Diagonal u[i] = wm_i*G_ii piggybacked on j==0 lanes.
__global__ __launch_bounds__(S_THREADS)
void k_sortscatter(const float* __restrict__ G, const float* __restrict__ w,
                   const float* __restrict__ mask, const int* __restrict__ nbr,
                   float* __restrict__ u, int* __restrict__ binCnt,
                   int2* __restrict__ pairs) {
    __shared__ int2 rec[EDGES_PER_BLOCK];    // 64 KB sorted record staging
    __shared__ int hist[LBINS], incl[LBINS], excl[LBINS], pos[LBINS], gb[LBINS];
    int tid = threadIdx.x;
    if (tid < LBINS) hist[tid] = 0;
    __syncthreads();

    long long blockStart = (long long)blockIdx.x * EDGES_PER_BLOCK;

    // ---- pass A: coalesced loads, values into registers, LDS histogram
    int nb[S_EPT];
    float val[S_EPT];
    #pragma unroll
    for (int e = 0; e < S_EPT; ++e) {
        long long t = blockStart + (long long)e * S_THREADS + tid;
        long long i = t / STENCIL;
        int j = (int)(t - i * STENCIL);
        int n = ntload(nbr + t);
        nb[e] = n;
        float wm = ntload(w + i) * ntload(mask + i);
        if (j == 0) u[i] = wm * ntload(G + i * 25);       // diagonal term
        val[e] = wm * ntload(G + i * 25 + 1 + j);
        if ((unsigned)n < (unsigned)NODE_N) atomicAdd(&hist[n >> 11], 1);
    }
    __syncthreads();

    // ---- inclusive scan over 128 bins (Hillis-Steele)
    if (tid < LBINS) incl[tid] = hist[tid];
    __syncthreads();
    for (int d = 1; d < LBINS; d <<= 1) {
        int x = 0;
        if (tid < LBINS && tid >= d) x = incl[tid - d];
        __syncthreads();
        if (tid < LBINS) incl[tid] += x;
        __syncthreads();
    }
    int batchBase = (blockStart >= (long long)NODE_N * STENCIL) ? LBINS : 0;
    if (tid < LBINS) {
        int h = hist[tid];
        int ex = incl[tid] - h;
        excl[tid] = ex;
        pos[tid]  = ex;
        gb[tid]   = h ? atomicAdd(&binCnt[batchBase + tid], h) : 0;
    }
    __syncthreads();

    // ---- pass B: scatter register records into LDS at sorted positions
    #pragma unroll
    for (int e = 0; e < S_EPT; ++e) {
        unsigned n = (unsigned)nb[e];
        if (n < (unsigned)NODE_N) {
            int b = (int)(n >> 11);
            int lp = atomicAdd(&pos[b], 1);
            rec[lp] = make_int2((int)(n & (BIN_NODES - 1)) | (b << 11),
                                __float_as_int(val[e]));
        }
    }
    __syncthreads();

    // ---- write-out: linear LDS read -> dense per-bin global runs
    int tot = incl[LBINS - 1];
    for (int s = tid; s < tot; s += S_THREADS) {
        int2 r = rec[s];
        int b = (r.x >> 11) & (LBINS - 1);
        int dst = gb[b] + (s - excl[b]);
        if (dst < BIN_CAP_G)
            pairs[(long long)(batchBase + b) * BIN_CAP_G + dst] =
                make_int2(r.x & (BIN_NODES - 1), r.y);
    }
}

// K4: one block per bin; LDS-accumulate dense pair stream, add to u
__global__ __launch_bounds__(1024)
void k_binaccum(const int* __restrict__ binCnt, const int2* __restrict__ pairs,
                float* __restrict__ u) {
    __shared__ float acc[BIN_NODES];
    int g = blockIdx.x, tid = threadIdx.x;
    for (int l = tid; l < BIN_NODES; l += 1024) acc[l] = 0.f;
    __syncthreads();
    int cnt = binCnt[g]; if (cnt > BIN_CAP_G) cnt = BIN_CAP_G;
    const i32x2* pb = (const i32x2*)(pairs + (long long)g * BIN_CAP_G);
    for (int s = tid; s < cnt; s += 1024) {
        i32x2 r = __builtin_nontemporal_load(pb + s);
        atomicAdd(&acc[r.x], __int_as_float(r.y));
    }
    __syncthreads();
    long long gbase = (long long)(g >> 7) * NODE_N + (long long)(g & (LBINS - 1)) * BIN_NODES;
    for (int l = tid; l < BIN_NODES; l += 1024)
        u[gbase + l] += acc[l];
}

// K5: v_i = u_i*G_ii + sum_j G_ij*u[nbr] + EPS*wm_i.
// Coalesced LDS staging of G + nbr rows (stride-25 pad: gcd(25,32)=1 ->
// conflict-free readback). Streams use nt loads; gathers stay cached.
__global__ __launch_bounds__(BLK)
void k_v(const float* __restrict__ G, const float* __restrict__ w,
         const float* __restrict__ mask, const int* __restrict__ nbr,
         const float* __restrict__ u, float* __restrict__ v, long long BN) {
    __shared__ float sg[BLK * 25];
    __shared__ int  snb[BLK * 25];
    int tid = threadIdx.x;
    long long base = (long long)blockIdx.x * BLK;
    int rows = (int)(((BN - base) < BLK) ? (BN - base) : BLK);
    const float* gsrc = G + base * 25;
    for (int k = tid; k < rows * 25; k += BLK) sg[k] = ntload(gsrc + k);
    const int* nsrc = nbr + base * STENCIL;
    for (int k = tid; k < rows * STENCIL; k += BLK) {
        int r = k / STENCIL, c = k - r * STENCIL;
        snb[r * 25 + c] = ntload(nsrc + k);
    }
    __syncthreads();
    if (tid >= rows) return;
    long long i = base + tid;
    const float* g  = sg + tid * 25;
    const int*   nn = snb + tid * 25;
    const float* ub = u + (i / NODE_N) * (long long)NODE_N;
    float acc = u[i] * g[0] + EPS_F * ntload(w + i) * ntload(mask + i);
    #pragma unroll
    for (int j = 0; j < STENCIL; ++j) {
        int n = nn[j];
        if ((unsigned)n < (unsigned)NODE_N) acc += g[1 + j] * ub[n];
    }
    v[i] = acc;
}

// K6: y = A*v; z = y/norm; per-block partial of ((z-wm)*mask)^2.
// Same staging structure as K5.
__global__ __launch_bounds__(BLK)
void k_y(const float* __restrict__ Ad, const float* __restrict__ Ao,
         const float* __restrict__ w, const float* __restrict__ mask,
         const int* __restrict__ nbr, const float* __restrict__ v,
         const double* __restrict__ scal, float* __restrict__ py, long long BN) {
    __shared__ float sa[BLK * 25];
    __shared__ int  snb[BLK * 25];
    int tid = threadIdx.x;
    long long base = (long long)blockIdx.x * BLK;
    int rows = (int)(((BN - base) < BLK) ? (BN - base) : BLK);
    const float* asrc = Ao + base * STENCIL;
    const int*   nsrc = nbr + base * STENCIL;
    for (int k = tid; k < rows * STENCIL; k += BLK) {
        int r = k / STENCIL, c = k - r * STENCIL;
        sa[r * 25 + c]  = ntload(asrc + k);
        snb[r * 25 + c] = ntload(nsrc + k);
    }
    __syncthreads();
    float dsq = 0.f;
    if (tid < rows) {
        long long i = base + tid;
        const float* a  = sa + tid * 25;
        const int*   nn = snb + tid * 25;
        const float* vb = v + (i / NODE_N) * (long long)NODE_N;
        float acc = v[i] * ntload(Ad + i);
        #pragma unroll
        for (int j = 0; j < STENCIL; ++j) {
            int n = nn[j];
            if ((unsigned)n < (unsigned)NODE_N) acc += a[j] * vb[n];
        }
        float z = acc / (float)(scal[0] + 1e-8);
        float m = ntload(mask + i);
        float d = (z - ntload(w + i) * m) * m;
        dsq = d * d;
    }
    float bs = block_reduce_f32(dsq);
    if (threadIdx.x == 0) py[blockIdx.x] = bs;
}

// K7: loss = sum(py)/(active+1e-6)
__global__ void k_final(const float* __restrict__ py, int nblk,
                        const double* __restrict__ scal, float* __restrict__ out) {
    float s = 0.f;
    for (int t = threadIdx.x; t < nblk; t += blockDim.x) s += py[t];
    float bs = block_reduce_f32(s);
    if (threadIdx.x == 0) out[0] = (float)((double)bs / (scal[1] + 1e-6));
}

// ---------------- fallback path (generic shapes): per-XCD privatized scatter --
__global__ void k_init_fb(const float* __restrict__ G, const float* __restrict__ w,
                          const float* __restrict__ mask, float* __restrict__ u, long long BN) {
    long long i = (long long)blockIdx.x * blockDim.x + threadIdx.x;
    if (i < BN) u[i] = w[i] * mask[i] * G[i * 25];
}
__global__ void k_scatter_fb(const float* __restrict__ G, const float* __restrict__ w,
                             const float* __restrict__ mask, const int* __restrict__ nbr,
                             float* __restrict__ ucopy, int N, long long BN) {
    long long t = (long long)blockIdx.x * blockDim.x + threadIdx.x;
    if (t >= BN * STENCIL) return;
    long long i = t / STENCIL;
    int j = (int)(t - i * STENCIL);
    int n = nbr[t];
    if ((unsigned)n >= (unsigned)N) return;
    float wm = w[i] * mask[i];
    float gv = G[i * 25 + 1 + j];
    float* ub = ucopy + (long long)get_xcc_id() * BN + (i / N) * (long long)N;
    __hip_atomic_fetch_add(&ub[n], wm * gv, __ATOMIC_RELAXED, __HIP_MEMORY_SCOPE_WORKGROUP);
}
__global__ void k_usum_fb(const float* __restrict__ ucopy, float* __restrict__ u, long long BN) {
    long long i = (long long)blockIdx.x * blockDim.x + threadIdx.x;
    if (i >= BN) return;
    float acc = u[i];
    #pragma unroll
    for (int c = 0; c < NXCD; ++c) acc += ucopy[(long long)c * BN + i];
    u[i] = acc;
}
// -----------------------------------------------------------------------------

extern "C" void kernel_launch(void* const* d_in, const int* in_sizes, int n_in,
                              void* d_out, int out_size, void* d_ws, size_t ws_size,
                              hipStream_t stream) {
    const float* G    = (const float*)d_in[0];
    const float* Ad   = (const float*)d_in[1];
    const float* Ao   = (const float*)d_in[2];
    const float* w    = (const float*)d_in[3];
    const float* mask = (const float*)d_in[4];
    const int*   nbr  = (const int*)d_in[5];

    const long long BN = in_sizes[3];
    const long long nEdges = BN * STENCIL;
    const int nodeBlocks = (int)((BN + BLK - 1) / BLK);

    // common ws: u, v, pn(1024), pa(1024), py(nodeBlocks)
    float* u  = (float*)d_ws;
    float* v  = u + BN;
    float* pn = v + BN;
    float* pa = pn + 1024;
    float* py = pa + 1024;
    char*  after_common = (char*)(py + nodeBlocks);

    // fast-path extra: binCnt(256) + pairs + scal
    int*  binCnt = (int*)(((uintptr_t)after_common + 15) & ~(uintptr_t)15);
    int2* pairs  = (int2*)(((uintptr_t)(binCnt + NBINS) + 7) & ~(uintptr_t)7);
    double* scal_fast = (double*)(((uintptr_t)(pairs + (long long)NBINS * BIN_CAP_G) + 7) & ~(uintptr_t)7);
    size_t need_fast = (size_t)((char*)(scal_fast + 2) - (char*)d_ws);

    // fallback extra: ucopy + scal
    float* ucopy = (float*)(((uintptr_t)after_common + 15) & ~(uintptr_t)15);
    double* scal_fb = (double*)(((uintptr_t)(ucopy + (long long)NXCD * BN) + 7) & ~(uintptr_t)7);

    bool fast = (BN == 2LL * NODE_N) && (ws_size >= need_fast);

    k_reduce<<<1024, BLK, 0, stream>>>(Ad, Ao, mask, BN, pn, pa);

    if (fast) {
        double* scal = scal_fast;
        k_scal<<<1, BLK, 0, stream>>>(pn, pa, 1024, scal);
        hipMemsetAsync(binCnt, 0, NBINS * sizeof(int), stream);
        int gridS = (int)(nEdges / EDGES_PER_BLOCK);     // 1536, divides exactly
        k_sortscatter<<<gridS, S_THREADS, 0, stream>>>(G, w, mask, nbr, u, binCnt, pairs);
        k_binaccum<<<NBINS, 1024, 0, stream>>>(binCnt, pairs, u);
        k_v<<<(int)(BN / BLK), BLK, 0, stream>>>(G, w, mask, nbr, u, v, BN);
        k_y<<<nodeBlocks, BLK, 0, stream>>>(Ad, Ao, w, mask, nbr, v, scal, py, BN);
        k_final<<<1, BLK, 0, stream>>>(py, nodeBlocks, scal, (float*)d_out);
    } else {
        double* scal = scal_fb;
        k_scal<<<1, BLK, 0, stream>>>(pn, pa, 1024, scal);
        hipMemsetAsync(ucopy, 0, (size_t)NXCD * BN * sizeof(float), stream);
        int edgeBlocks = (int)((nEdges + BLK - 1) / BLK);
        k_init_fb<<<nodeBlocks, BLK, 0, stream>>>(G, w, mask, u, BN);
        k_scatter_fb<<<edgeBlocks, BLK, 0, stream>>>(G, w, mask, nbr, ucopy, NODE_N, BN);
        k_usum_fb<<<nodeBlocks, BLK, 0, stream>>>(ucopy, u, BN);
        k_v<<<nodeBlocks, BLK, 0, stream>>>(G, w, mask, nbr, u, v, BN);
        k_y<<<nodeBlocks, BLK, 0, stream>>>(Ad, Ao, w, mask, nbr, v, scal, py, BN);
        k_final<<<1, BLK, 0, stream>>>(py, nodeBlocks, scal, (float*)d_out);
    }
}

// Round 6
// 478.407 us; speedup vs baseline: 1.1104x; 1.1104x over previous
//
#include <hip/hip_runtime.h>
#include <stdint.h>

#define STENCIL 24
#define EPS_F 1e-4f
#define BLK 256
#define NXCD 8

#define NODE_N 262144                       // nodes per batch (fixed problem size)
#define BIN_NODES 2048                      // nodes per bin (LDS accumulator)
#define LBINS 128                           // bins per batch
#define NBINS 256                           // 2 batches * 128
#define BIN_CAP_G 49152                     // per-bin pair capacity: mean 47722, +6.5 sigma

#define S_THREADS 512
#define S_EPT 16
#define EDGES_PER_BLOCK (S_THREADS * S_EPT) // 8192

typedef int   i32x2 __attribute__((ext_vector_type(2)));

// nontemporal load: stream hint so big one-pass arrays don't evict the small
// gather targets (u/v, 1 MB each) from L2. Use ONLY for true single-use data.
template <typename T>
static __device__ __forceinline__ T ntload(const T* p) {
    return __builtin_nontemporal_load(p);
}

// ---- XCD id (fallback path only), verified gfx950 (learn_hip m09)
static __device__ __forceinline__ int get_xcc_id() {
    int x;
    asm volatile("s_getreg_b32 %0, hwreg(HW_REG_XCC_ID)" : "=s"(x));
    return x & (NXCD - 1);
}

__device__ __forceinline__ float wave_reduce_f32(float v) {
    #pragma unroll
    for (int off = 32; off > 0; off >>= 1)
        v += __shfl_down(v, off, 64);
    return v;
}

__device__ __forceinline__ float block_reduce_f32(float v) {
    __shared__ float sw[BLK / 64];
    float s = wave_reduce_f32(v);
    if ((threadIdx.x & 63) == 0) sw[threadIdx.x >> 6] = s;
    __syncthreads();
    float r = 0.f;
    if (threadIdx.x == 0) {
        #pragma unroll
        for (int k = 0; k < BLK / 64; ++k) r += sw[k];
    }
    return r;
}

// K1: per-block partials of sum|A| and sum(mask)
__global__ void k_reduce(const float* __restrict__ Ad, const float* __restrict__ Ao,
                         const float* __restrict__ mask, long long BN,
                         float* __restrict__ pn, float* __restrict__ pa) {
    long long total = BN * STENCIL;
    long long stride = (long long)gridDim.x * blockDim.x;
    float s = 0.f, act = 0.f;
    for (long long t = (long long)blockIdx.x * blockDim.x + threadIdx.x; t < total; t += stride) {
        s += fabsf(ntload(Ao + t));
        if (t < BN) { s += fabsf(ntload(Ad + t)); act += ntload(mask + t); }
    }
    float bs = block_reduce_f32(s);
    if (threadIdx.x == 0) pn[blockIdx.x] = bs;
    __syncthreads();
    float ba = block_reduce_f32(act);
    if (threadIdx.x == 0) pa[blockIdx.x] = ba;
}

// K2: scal[0]=norm_A, scal[1]=active
__global__ void k_scal(const float* __restrict__ pn, const float* __restrict__ pa,
                       int nblk, double* __restrict__ scal) {
    float sn = 0.f, sa = 0.f;
    for (int t = threadIdx.x; t < nblk; t += blockDim.x) { sn += pn[t]; sa += pa[t]; }
    float bn_ = block_reduce_f32(sn);
    __shared__ double dn;
    if (threadIdx.x == 0) dn = (double)bn_;
    __syncthreads();
    float ba = block_reduce_f32(sa);
    if (threadIdx.x == 0) {
        double act = (double)ba;
        scal[0] = dn / (act * 25.0 + 1e-6);
        scal[1] = act;
    }
}

// K3: block counting-sort of edges by target bin; dense pair write-out.
// BLOCKED mapping (R3, proven): thread covers 16 contiguous edges; a wave
// covers a contiguous 4KB span -> aggregate-coalesced, L1-served. Plain
// cached loads (L1 reuse matters here; nt regressed this kernel in R5).
// Diagonal u[i] = wm_i*G_ii piggybacked on j==0 edges.
__global__ __launch_bounds__(S_THREADS)
void k_sortscatter(const float* __restrict__ G, const float* __restrict__ w,
                   const float* __restrict__ mask, const int* __restrict__ nbr,
                   float* __restrict__ u, int* __restrict__ binCnt,
                   int2* __restrict__ pairs) {
    __shared__ int2 rec[EDGES_PER_BLOCK];    // 64 KB sorted record staging
    __shared__ int hist[LBINS], incl[LBINS], excl[LBINS], pos[LBINS], gb[LBINS];
    int tid = threadIdx.x;
    if (tid < LBINS) hist[tid] = 0;
    __syncthreads();

    long long blockStart = (long long)blockIdx.x * EDGES_PER_BLOCK;
    long long t0 = blockStart + (long long)tid * S_EPT;

    // ---- pass A: neighbors into registers (int4 x4), LDS histogram
    int nb[S_EPT];
    const int4* p4 = (const int4*)(nbr + t0);            // t0 % 16 == 0 -> aligned
    #pragma unroll
    for (int q = 0; q < S_EPT / 4; ++q) {
        int4 x = p4[q];
        nb[q*4] = x.x; nb[q*4+1] = x.y; nb[q*4+2] = x.z; nb[q*4+3] = x.w;
    }
    #pragma unroll
    for (int e = 0; e < S_EPT; ++e) {
        unsigned n = (unsigned)nb[e];
        if (n < (unsigned)NODE_N) atomicAdd(&hist[n >> 11], 1);
    }
    __syncthreads();

    // ---- inclusive scan over 128 bins (Hillis-Steele)
    if (tid < LBINS) incl[tid] = hist[tid];
    __syncthreads();
    for (int d = 1; d < LBINS; d <<= 1) {
        int x = 0;
        if (tid < LBINS && tid >= d) x = incl[tid - d];
        __syncthreads();
        if (tid < LBINS) incl[tid] += x;
        __syncthreads();
    }
    int batchBase = (blockStart >= (long long)NODE_N * STENCIL) ? LBINS : 0;
    if (tid < LBINS) {
        int h = hist[tid];
        int ex = incl[tid] - h;
        excl[tid] = ex;
        pos[tid]  = ex;
        gb[tid]   = h ? atomicAdd(&binCnt[batchBase + tid], h) : 0;
    }
    __syncthreads();

    // ---- pass B: values + diag, scatter records into LDS at sorted positions
    long long i0 = t0 / STENCIL;
    long long i1 = (t0 + S_EPT - 1) / STENCIL;           // spans at most 2 rows
    float wm0 = w[i0] * mask[i0];
    float wm1 = (i1 != i0) ? w[i1] * mask[i1] : wm0;
    long long i = i0;
    int j = (int)(t0 - i0 * STENCIL);
    #pragma unroll
    for (int e = 0; e < S_EPT; ++e) {
        float wm = (i == i0) ? wm0 : wm1;
        if (j == 0) u[i] = wm * G[i * 25];               // diagonal term
        unsigned n = (unsigned)nb[e];
        if (n < (unsigned)NODE_N) {
            int b = (int)(n >> 11);
            float val = wm * G[i * 25 + 1 + j];
            int lp = atomicAdd(&pos[b], 1);
            rec[lp] = make_int2((int)(n & (BIN_NODES - 1)) | (b << 11), __float_as_int(val));
        }
        if (++j == STENCIL) { j = 0; ++i; }
    }
    __syncthreads();

    // ---- write-out: linear LDS read -> dense per-bin global runs
    int tot = incl[LBINS - 1];
    for (int s = tid; s < tot; s += S_THREADS) {
        int2 r = rec[s];
        int b = (r.x >> 11) & (LBINS - 1);
        int dst = gb[b] + (s - excl[b]);
        if (dst < BIN_CAP_G)
            pairs[(long long)(batchBase + b) * BIN_CAP_G + dst] =
                make_int2(r.x & (BIN_NODES - 1), r.y);
    }
}

// K4: one block per bin; 4-way replicated LDS accumulators (replica = tid&3,
// stride 2049 de-phases banks) to cut same-address atomic serialization 4x.
__global__ __launch_bounds__(1024)
void k_binaccum(const int* __restrict__ binCnt, const int2* __restrict__ pairs,
                float* __restrict__ u) {
    __shared__ float acc[4][BIN_NODES + 1];  // 32.8 KB
    int g = blockIdx.x, tid = threadIdx.x;
    for (int l = tid; l < BIN_NODES; l += 1024) {
        acc[0][l] = 0.f; acc[1][l] = 0.f; acc[2][l] = 0.f; acc[3][l] = 0.f;
    }
    __syncthreads();
    int cnt = binCnt[g]; if (cnt > BIN_CAP_G) cnt = BIN_CAP_G;
    const i32x2* pb = (const i32x2*)(pairs + (long long)g * BIN_CAP_G);
    int rep = tid & 3;
    for (int s = tid; s < cnt; s += 1024) {
        i32x2 r = __builtin_nontemporal_load(pb + s);
        atomicAdd(&acc[rep][r.x], __int_as_float(r.y));
    }
    __syncthreads();
    long long gbase = (long long)(g >> 7) * NODE_N + (long long)(g & (LBINS - 1)) * BIN_NODES;
    for (int l = tid; l < BIN_NODES; l += 1024)
        u[gbase + l] += acc[0][l] + acc[1][l] + acc[2][l] + acc[3][l];
}

// K5: v_i = u_i*G_ii + sum_j G_ij*u[nbr] + EPS*wm_i.
// Coalesced LDS staging of G + nbr rows (stride-25: gcd(25,32)=1 ->
// conflict-free readback). Streams via nt; gathers stay cached.
__global__ __launch_bounds__(BLK)
void k_v(const float* __restrict__ G, const float* __restrict__ w,
         const float* __restrict__ mask, const int* __restrict__ nbr,
         const float* __restrict__ u, float* __restrict__ v, long long BN) {
    __shared__ float sg[BLK * 25];
    __shared__ int  snb[BLK * 25];
    int tid = threadIdx.x;
    long long base = (long long)blockIdx.x * BLK;
    int rows = (int)(((BN - base) < BLK) ? (BN - base) : BLK);
    const float* gsrc = G + base * 25;
    for (int k = tid; k < rows * 25; k += BLK) sg[k] = ntload(gsrc + k);
    const int* nsrc = nbr + base * STENCIL;
    for (int k = tid; k < rows * STENCIL; k += BLK) {
        int r = k / STENCIL, c = k - r * STENCIL;
        snb[r * 25 + c] = ntload(nsrc + k);
    }
    __syncthreads();
    if (tid >= rows) return;
    long long i = base + tid;
    const float* g  = sg + tid * 25;
    const int*   nn = snb + tid * 25;
    const float* ub = u + (i / NODE_N) * (long long)NODE_N;
    float acc = u[i] * g[0] + EPS_F * ntload(w + i) * ntload(mask + i);
    #pragma unroll
    for (int j = 0; j < STENCIL; ++j) {
        int n = nn[j];
        if ((unsigned)n < (unsigned)NODE_N) acc += g[1 + j] * ub[n];
    }
    v[i] = acc;
}

// K6: y = A*v; z = y/norm; per-block partial of ((z-wm)*mask)^2.
__global__ __launch_bounds__(BLK)
void k_y(const float* __restrict__ Ad, const float* __restrict__ Ao,
         const float* __restrict__ w, const float* __restrict__ mask,
         const int* __restrict__ nbr, const float* __restrict__ v,
         const double* __restrict__ scal, float* __restrict__ py, long long BN) {
    __shared__ float sa[BLK * 25];
    __shared__ int  snb[BLK * 25];
    int tid = threadIdx.x;
    long long base = (long long)blockIdx.x * BLK;
    int rows = (int)(((BN - base) < BLK) ? (BN - base) : BLK);
    const float* asrc = Ao + base * STENCIL;
    const int*   nsrc = nbr + base * STENCIL;
    for (int k = tid; k < rows * STENCIL; k += BLK) {
        int r = k / STENCIL, c = k - r * STENCIL;
        sa[r * 25 + c]  = ntload(asrc + k);
        snb[r * 25 + c] = ntload(nsrc + k);
    }
    __syncthreads();
    float dsq = 0.f;
    if (tid < rows) {
        long long i = base + tid;
        const float* a  = sa + tid * 25;
        const int*   nn = snb + tid * 25;
        const float* vb = v + (i / NODE_N) * (long long)NODE_N;
        float acc = v[i] * ntload(Ad + i);
        #pragma unroll
        for (int j = 0; j < STENCIL; ++j) {
            int n = nn[j];
            if ((unsigned)n < (unsigned)NODE_N) acc += a[j] * vb[n];
        }
        float z = acc / (float)(scal[0] + 1e-8);
        float m = ntload(mask + i);
        float d = (z - ntload(w + i) * m) * m;
        dsq = d * d;
    }
    float bs = block_reduce_f32(dsq);
    if (threadIdx.x == 0) py[blockIdx.x] = bs;
}

// K7: loss = sum(py)/(active+1e-6)
__global__ void k_final(const float* __restrict__ py, int nblk,
                        const double* __restrict__ scal, float* __restrict__ out) {
    float s = 0.f;
    for (int t = threadIdx.x; t < nblk; t += blockDim.x) s += py[t];
    float bs = block_reduce_f32(s);
    if (threadIdx.x == 0) out[0] = (float)((double)bs / (scal[1] + 1e-6));
}

// ---------------- fallback path (generic shapes): per-XCD privatized scatter --
__global__ void k_init_fb(const float* __restrict__ G, const float* __restrict__ w,
                          const float* __restrict__ mask, float* __restrict__ u, long long BN) {
    long long i = (long long)blockIdx.x * blockDim.x + threadIdx.x;
    if (i < BN) u[i] = w[i] * mask[i] * G[i * 25];
}
__global__ void k_scatter_fb(const float* __restrict__ G, const float* __restrict__ w,
                             const float* __restrict__ mask, const int* __restrict__ nbr,
                             float* __restrict__ ucopy, int N, long long BN) {
    long long t = (long long)blockIdx.x * blockDim.x + threadIdx.x;
    if (t >= BN * STENCIL) return;
    long long i = t / STENCIL;
    int j = (int)(t - i * STENCIL);
    int n = nbr[t];
    if ((unsigned)n >= (unsigned)N) return;
    float wm = w[i] * mask[i];
    float gv = G[i * 25 + 1 + j];
    float* ub = ucopy + (long long)get_xcc_id() * BN + (i / N) * (long long)N;
    __hip_atomic_fetch_add(&ub[n], wm * gv, __ATOMIC_RELAXED, __HIP_MEMORY_SCOPE_WORKGROUP);
}
__global__ void k_usum_fb(const float* __restrict__ ucopy, float* __restrict__ u, long long BN) {
    long long i = (long long)blockIdx.x * blockDim.x + threadIdx.x;
    if (i >= BN) return;
    float acc = u[i];
    #pragma unroll
    for (int c = 0; c < NXCD; ++c) acc += ucopy[(long long)c * BN + i];
    u[i] = acc;
}
// -----------------------------------------------------------------------------

extern "C" void kernel_launch(void* const* d_in, const int* in_sizes, int n_in,
                              void* d_out, int out_size, void* d_ws, size_t ws_size,
                              hipStream_t stream) {
    const float* G    = (const float*)d_in[0];
    const float* Ad   = (const float*)d_in[1];
    const float* Ao   = (const float*)d_in[2];
    const float* w    = (const float*)d_in[3];
    const float* mask = (const float*)d_in[4];
    const int*   nbr  = (const int*)d_in[5];

    const long long BN = in_sizes[3];
    const long long nEdges = BN * STENCIL;
    const int nodeBlocks = (int)((BN + BLK - 1) / BLK);

    // common ws: u, v, pn(1024), pa(1024), py(nodeBlocks)
    float* u  = (float*)d_ws;
    float* v  = u + BN;
    float* pn = v + BN;
    float* pa = pn + 1024;
    float* py = pa + 1024;
    char*  after_common = (char*)(py + nodeBlocks);

    // fast-path extra: binCnt(256) + pairs + scal
    int*  binCnt = (int*)(((uintptr_t)after_common + 15) & ~(uintptr_t)15);
    int2* pairs  = (int2*)(((uintptr_t)(binCnt + NBINS) + 7) & ~(uintptr_t)7);
    double* scal_fast = (double*)(((uintptr_t)(pairs + (long long)NBINS * BIN_CAP_G) + 7) & ~(uintptr_t)7);
    size_t need_fast = (size_t)((char*)(scal_fast + 2) - (char*)d_ws);

    // fallback extra: ucopy + scal
    float* ucopy = (float*)(((uintptr_t)after_common + 15) & ~(uintptr_t)15);
    double* scal_fb = (double*)(((uintptr_t)(ucopy + (long long)NXCD * BN) + 7) & ~(uintptr_t)7);

    bool fast = (BN == 2LL * NODE_N) && (ws_size >= need_fast);

    k_reduce<<<1024, BLK, 0, stream>>>(Ad, Ao, mask, BN, pn, pa);

    if (fast) {
        double* scal = scal_fast;
        k_scal<<<1, BLK, 0, stream>>>(pn, pa, 1024, scal);
        hipMemsetAsync(binCnt, 0, NBINS * sizeof(int), stream);
        int gridS = (int)(nEdges / EDGES_PER_BLOCK);     // 1536, divides exactly
        k_sortscatter<<<gridS, S_THREADS, 0, stream>>>(G, w, mask, nbr, u, binCnt, pairs);
        k_binaccum<<<NBINS, 1024, 0, stream>>>(binCnt, pairs, u);
        k_v<<<(int)(BN / BLK), BLK, 0, stream>>>(G, w, mask, nbr, u, v, BN);
        k_y<<<nodeBlocks, BLK, 0, stream>>>(Ad, Ao, w, mask, nbr, v, scal, py, BN);
        k_final<<<1, BLK, 0, stream>>>(py, nodeBlocks, scal, (float*)d_out);
    } else {
        double* scal = scal_fb;
        k_scal<<<1, BLK, 0, stream>>>(pn, pa, 1024, scal);
        hipMemsetAsync(ucopy, 0, (size_t)NXCD * BN * sizeof(float), stream);
        int edgeBlocks = (int)((nEdges + BLK - 1) / BLK);
        k_init_fb<<<nodeBlocks, BLK, 0, stream>>>(G, w, mask, u, BN);
        k_scatter_fb<<<edgeBlocks, BLK, 0, stream>>>(G, w, mask, nbr, ucopy, NODE_N, BN);
        k_usum_fb<<<nodeBlocks, BLK, 0, stream>>>(ucopy, u, BN);
        k_v<<<nodeBlocks, BLK, 0, stream>>>(G, w, mask, nbr, u, v, BN);
        k_y<<<nodeBlocks, BLK, 0, stream>>>(Ad, Ao, w, mask, nbr, v, scal, py, BN);
        k_final<<<1, BLK, 0, stream>>>(py, nodeBlocks, scal, (float*)d_out);
    }
}

// Round 7
// 407.439 us; speedup vs baseline: 1.3039x; 1.1742x over previous
//
#include <hip/hip_runtime.h>
#include <stdint.h>

#define STENCIL 24
#define EPS_F 1e-4f
#define BLK 256
#define NXCD 8

#define NODE_N 262144                       // nodes per batch (fixed problem size)
#define BIN_NODES 2048                      // nodes per bin (LDS accumulator)
#define LBINS 128                           // bins per batch
#define NBINS 256                           // 2 batches * 128
#define BIN_CAP_G 49152                     // per-bin pair capacity: mean 47722, +6.5 sigma

#define S_THREADS 512
#define S_EPT 8
#define EDGES_PER_BLOCK (S_THREADS * S_EPT) // 4096; rec=32KB -> 4 blocks/CU

typedef int   i32x2 __attribute__((ext_vector_type(2)));

// nontemporal load: stream hint so big one-pass arrays don't evict the small
// gather targets (u/v, 1 MB each) from L2/L3.
template <typename T>
static __device__ __forceinline__ T ntload(const T* p) {
    return __builtin_nontemporal_load(p);
}

// ---- XCD id (fallback path only), verified gfx950 (learn_hip m09)
static __device__ __forceinline__ int get_xcc_id() {
    int x;
    asm volatile("s_getreg_b32 %0, hwreg(HW_REG_XCC_ID)" : "=s"(x));
    return x & (NXCD - 1);
}

__device__ __forceinline__ float wave_reduce_f32(float v) {
    #pragma unroll
    for (int off = 32; off > 0; off >>= 1)
        v += __shfl_down(v, off, 64);
    return v;
}

// 5-component block(256) reduce, single barrier; out[] valid on thread 0
__device__ __forceinline__ void block_reduce5(float v[5], float out[5]) {
    __shared__ float sw[4][5];
    #pragma unroll
    for (int c = 0; c < 5; ++c) v[c] = wave_reduce_f32(v[c]);
    if ((threadIdx.x & 63) == 0) {
        #pragma unroll
        for (int c = 0; c < 5; ++c) sw[threadIdx.x >> 6][c] = v[c];
    }
    __syncthreads();
    if (threadIdx.x == 0) {
        #pragma unroll
        for (int c = 0; c < 5; ++c)
            out[c] = sw[0][c] + sw[1][c] + sw[2][c] + sw[3][c];
    }
}

// K3: block counting-sort of edges by target bin; dense pair write-out.
// BLOCKED mapping (proven R3/R4): thread covers 8 contiguous edges; a wave
// covers a contiguous 2KB span -> aggregate-coalesced, L1-served.
// Diagonal u[i] = wm_i*G_ii piggybacked on j==0 edges.
__global__ __launch_bounds__(S_THREADS)
void k_sortscatter(const float* __restrict__ G, const float* __restrict__ w,
                   const float* __restrict__ mask, const int* __restrict__ nbr,
                   float* __restrict__ u, int* __restrict__ binCnt,
                   int2* __restrict__ pairs) {
    __shared__ int2 rec[EDGES_PER_BLOCK];    // 32 KB sorted record staging
    __shared__ int hist[LBINS], incl[LBINS], excl[LBINS], pos[LBINS], gb[LBINS];
    int tid = threadIdx.x;
    if (tid < LBINS) hist[tid] = 0;
    __syncthreads();

    long long blockStart = (long long)blockIdx.x * EDGES_PER_BLOCK;
    long long t0 = blockStart + (long long)tid * S_EPT;

    // ---- pass A: neighbors into registers (int4 x2), LDS histogram
    int nb[S_EPT];
    const int4* p4 = (const int4*)(nbr + t0);            // t0 % 16 == 0 -> aligned
    #pragma unroll
    for (int q = 0; q < S_EPT / 4; ++q) {
        int4 x = p4[q];
        nb[q*4] = x.x; nb[q*4+1] = x.y; nb[q*4+2] = x.z; nb[q*4+3] = x.w;
    }
    #pragma unroll
    for (int e = 0; e < S_EPT; ++e) {
        unsigned n = (unsigned)nb[e];
        if (n < (unsigned)NODE_N) atomicAdd(&hist[n >> 11], 1);
    }
    __syncthreads();

    // ---- inclusive scan over 128 bins (Hillis-Steele)
    if (tid < LBINS) incl[tid] = hist[tid];
    __syncthreads();
    for (int d = 1; d < LBINS; d <<= 1) {
        int x = 0;
        if (tid < LBINS && tid >= d) x = incl[tid - d];
        __syncthreads();
        if (tid < LBINS) incl[tid] += x;
        __syncthreads();
    }
    int batchBase = (blockStart >= (long long)NODE_N * STENCIL) ? LBINS : 0;
    if (tid < LBINS) {
        int h = hist[tid];
        int ex = incl[tid] - h;
        excl[tid] = ex;
        pos[tid]  = ex;
        gb[tid]   = h ? atomicAdd(&binCnt[batchBase + tid], h) : 0;
    }
    __syncthreads();

    // ---- pass B: values + diag, scatter records into LDS at sorted positions
    long long i0 = t0 / STENCIL;
    long long i1 = (t0 + S_EPT - 1) / STENCIL;           // spans at most 2 rows
    float wm0 = w[i0] * mask[i0];
    float wm1 = (i1 != i0) ? w[i1] * mask[i1] : wm0;
    long long i = i0;
    int j = (int)(t0 - i0 * STENCIL);
    #pragma unroll
    for (int e = 0; e < S_EPT; ++e) {
        float wm = (i == i0) ? wm0 : wm1;
        if (j == 0) u[i] = wm * G[i * 25];               // diagonal term
        unsigned n = (unsigned)nb[e];
        if (n < (unsigned)NODE_N) {
            int b = (int)(n >> 11);
            float val = wm * G[i * 25 + 1 + j];
            int lp = atomicAdd(&pos[b], 1);
            rec[lp] = make_int2((int)(n & (BIN_NODES - 1)) | (b << 11), __float_as_int(val));
        }
        if (++j == STENCIL) { j = 0; ++i; }
    }
    __syncthreads();

    // ---- write-out: linear LDS read -> dense per-bin global runs
    int tot = incl[LBINS - 1];
    for (int s = tid; s < tot; s += S_THREADS) {
        int2 r = rec[s];
        int b = (r.x >> 11) & (LBINS - 1);
        int dst = gb[b] + (s - excl[b]);
        if (dst < BIN_CAP_G)
            pairs[(long long)(batchBase + b) * BIN_CAP_G + dst] =
                make_int2(r.x & (BIN_NODES - 1), r.y);
    }
}

// K4: one block per bin; 4-way replicated LDS accumulators (LDS-throughput
// bound: ~48K atomics/CU; replication removes same-address serialization).
__global__ __launch_bounds__(1024)
void k_binaccum(const int* __restrict__ binCnt, const int2* __restrict__ pairs,
                float* __restrict__ u) {
    __shared__ float acc[4][BIN_NODES + 1];  // 32.8 KB
    int g = blockIdx.x, tid = threadIdx.x;
    for (int l = tid; l < BIN_NODES; l += 1024) {
        acc[0][l] = 0.f; acc[1][l] = 0.f; acc[2][l] = 0.f; acc[3][l] = 0.f;
    }
    __syncthreads();
    int cnt = binCnt[g]; if (cnt > BIN_CAP_G) cnt = BIN_CAP_G;
    const i32x2* pb = (const i32x2*)(pairs + (long long)g * BIN_CAP_G);
    int rep = tid & 3;
    for (int s = tid; s < cnt; s += 1024) {
        i32x2 r = __builtin_nontemporal_load(pb + s);
        atomicAdd(&acc[rep][r.x], __int_as_float(r.y));
    }
    __syncthreads();
    long long gbase = (long long)(g >> 7) * NODE_N + (long long)(g & (LBINS - 1)) * BIN_NODES;
    for (int l = tid; l < BIN_NODES; l += 1024)
        u[gbase + l] += acc[0][l] + acc[1][l] + acc[2][l] + acc[3][l];
}

// K5: v_i = u_i*G_ii + sum_j G_ij*u[nbr] + EPS*wm_i.
// G rows staged via LDS (stride-25: gcd(25,32)=1, conflict-free readback);
// nbr direct int4 to registers. LDS 25.6KB -> 6 blocks/CU.
__global__ __launch_bounds__(BLK)
void k_v(const float* __restrict__ G, const float* __restrict__ w,
         const float* __restrict__ mask, const int* __restrict__ nbr,
         const float* __restrict__ u, float* __restrict__ v, long long BN) {
    __shared__ float sg[BLK * 25];
    int tid = threadIdx.x;
    long long base = (long long)blockIdx.x * BLK;
    int rows = (int)(((BN - base) < BLK) ? (BN - base) : BLK);
    const float* gsrc = G + base * 25;
    for (int k = tid; k < rows * 25; k += BLK) sg[k] = ntload(gsrc + k);
    __syncthreads();
    if (tid >= rows) return;
    long long i = base + tid;
    const int4* nb4 = (const int4*)(nbr + i * STENCIL);  // 96B rows, 16B aligned
    int nn[24];
    #pragma unroll
    for (int q = 0; q < 6; ++q) {
        int4 x = nb4[q];
        nn[q*4] = x.x; nn[q*4+1] = x.y; nn[q*4+2] = x.z; nn[q*4+3] = x.w;
    }
    const float* g  = sg + tid * 25;
    const float* ub = u + (i / NODE_N) * (long long)NODE_N;
    float acc = u[i] * g[0] + EPS_F * ntload(w + i) * ntload(mask + i);
    #pragma unroll
    for (int j = 0; j < STENCIL; ++j) {
        int n = nn[j];
        if ((unsigned)n < (unsigned)NODE_N) acc += g[1 + j] * ub[n];
    }
    v[i] = acc;
}

// K6 (fused): y = A*v; loss partials via algebraic split (no norm needed here):
//   d = (y/nrm - w*m)*m  =>  d^2 = P^2/nrm^2 - 2PQ/nrm + Q^2, P=y*m, Q=w*m^2.
// Also computes the |A| and mask sums (Ad/Ao stream through here anyway).
// Per-block partials: py[0*NB+b]=sum|A|, [1]=sum(m), [2]=sum P^2, [3]=sum PQ, [4]=sum Q^2.
__global__ __launch_bounds__(BLK)
void k_y(const float* __restrict__ Ad, const float* __restrict__ Ao,
         const float* __restrict__ w, const float* __restrict__ mask,
         const int* __restrict__ nbr, const float* __restrict__ v,
         float* __restrict__ py, int nblk, long long BN) {
    __shared__ float sa[BLK * 25];
    int tid = threadIdx.x;
    long long base = (long long)blockIdx.x * BLK;
    int rows = (int)(((BN - base) < BLK) ? (BN - base) : BLK);
    const float* asrc = Ao + base * STENCIL;
    float asum = 0.f;
    for (int k = tid; k < rows * STENCIL; k += BLK) {
        float x = ntload(asrc + k);
        asum += fabsf(x);
        int r = k / STENCIL, c = k - r * STENCIL;
        sa[r * 25 + c] = x;
    }
    __syncthreads();
    float part[5] = {asum, 0.f, 0.f, 0.f, 0.f};
    if (tid < rows) {
        long long i = base + tid;
        const int4* nb4 = (const int4*)(nbr + i * STENCIL);
        int nn[24];
        #pragma unroll
        for (int q = 0; q < 6; ++q) {
            int4 x = nb4[q];
            nn[q*4] = x.x; nn[q*4+1] = x.y; nn[q*4+2] = x.z; nn[q*4+3] = x.w;
        }
        float ad = ntload(Ad + i);
        part[0] += fabsf(ad);
        const float* a  = sa + tid * 25;
        const float* vb = v + (i / NODE_N) * (long long)NODE_N;
        float acc = v[i] * ad;
        #pragma unroll
        for (int j = 0; j < STENCIL; ++j) {
            int n = nn[j];
            if ((unsigned)n < (unsigned)NODE_N) acc += a[j] * vb[n];
        }
        float m = ntload(mask + i);
        float P = acc * m;                    // y*m
        float Q = ntload(w + i) * m * m;      // w*m^2
        part[1] = m;
        part[2] = P * P;
        part[3] = P * Q;
        part[4] = Q * Q;
    }
    float out[5];
    block_reduce5(part, out);
    if (tid == 0) {
        #pragma unroll
        for (int c = 0; c < 5; ++c) py[(long long)c * nblk + blockIdx.x] = out[c];
    }
}

// K7: final reduce of 5 partial arrays + norm algebra.
__global__ __launch_bounds__(1024)
void k_final(const float* __restrict__ py, int nblk, float* __restrict__ out) {
    __shared__ float sw[16][5];
    __shared__ float res[5];
    float part[5] = {0.f, 0.f, 0.f, 0.f, 0.f};
    for (int t = threadIdx.x; t < nblk; t += 1024) {
        #pragma unroll
        for (int c = 0; c < 5; ++c) part[c] += py[(long long)c * nblk + t];
    }
    #pragma unroll
    for (int c = 0; c < 5; ++c) part[c] = wave_reduce_f32(part[c]);
    if ((threadIdx.x & 63) == 0) {
        #pragma unroll
        for (int c = 0; c < 5; ++c) sw[threadIdx.x >> 6][c] = part[c];
    }
    __syncthreads();
    if (threadIdx.x == 0) {
        #pragma unroll
        for (int c = 0; c < 5; ++c) {
            float r = 0.f;
            for (int k = 0; k < 16; ++k) r += sw[k][c];
            res[c] = r;
        }
        double A   = res[0], act = res[1];
        double a   = res[2], b   = res[3], c2 = res[4];
        double nrm = A / (act * 25.0 + 1e-6) + 1e-8;
        double loss = (a / (nrm * nrm) - 2.0 * b / nrm + c2) / (act + 1e-6);
        out[0] = (float)loss;
    }
}

// ---------------- fallback path (generic shapes): per-XCD privatized scatter --
__global__ void k_init_fb(const float* __restrict__ G, const float* __restrict__ w,
                          const float* __restrict__ mask, float* __restrict__ u, long long BN) {
    long long i = (long long)blockIdx.x * blockDim.x + threadIdx.x;
    if (i < BN) u[i] = w[i] * mask[i] * G[i * 25];
}
__global__ void k_scatter_fb(const float* __restrict__ G, const float* __restrict__ w,
                             const float* __restrict__ mask, const int* __restrict__ nbr,
                             float* __restrict__ ucopy, int N, long long BN) {
    long long t = (long long)blockIdx.x * blockDim.x + threadIdx.x;
    if (t >= BN * STENCIL) return;
    long long i = t / STENCIL;
    int j = (int)(t - i * STENCIL);
    int n = nbr[t];
    if ((unsigned)n >= (unsigned)N) return;
    float wm = w[i] * mask[i];
    float gv = G[i * 25 + 1 + j];
    float* ub = ucopy + (long long)get_xcc_id() * BN + (i / N) * (long long)N;
    __hip_atomic_fetch_add(&ub[n], wm * gv, __ATOMIC_RELAXED, __HIP_MEMORY_SCOPE_WORKGROUP);
}
__global__ void k_usum_fb(const float* __restrict__ ucopy, float* __restrict__ u, long long BN) {
    long long i = (long long)blockIdx.x * blockDim.x + threadIdx.x;
    if (i >= BN) return;
    float acc = u[i];
    #pragma unroll
    for (int c = 0; c < NXCD; ++c) acc += ucopy[(long long)c * BN + i];
    u[i] = acc;
}
// -----------------------------------------------------------------------------

extern "C" void kernel_launch(void* const* d_in, const int* in_sizes, int n_in,
                              void* d_out, int out_size, void* d_ws, size_t ws_size,
                              hipStream_t stream) {
    const float* G    = (const float*)d_in[0];
    const float* Ad   = (const float*)d_in[1];
    const float* Ao   = (const float*)d_in[2];
    const float* w    = (const float*)d_in[3];
    const float* mask = (const float*)d_in[4];
    const int*   nbr  = (const int*)d_in[5];

    const long long BN = in_sizes[3];
    const long long nEdges = BN * STENCIL;
    const int nodeBlocks = (int)((BN + BLK - 1) / BLK);

    // common ws: u, v, py(5*nodeBlocks)
    float* u  = (float*)d_ws;
    float* v  = u + BN;
    float* py = v + BN;
    char*  after_common = (char*)(py + 5LL * nodeBlocks);

    // fast-path extra: binCnt(256) + pairs
    int*  binCnt = (int*)(((uintptr_t)after_common + 15) & ~(uintptr_t)15);
    int2* pairs  = (int2*)(((uintptr_t)(binCnt + NBINS) + 7) & ~(uintptr_t)7);
    size_t need_fast = (size_t)((char*)(pairs + (long long)NBINS * BIN_CAP_G) - (char*)d_ws);

    // fallback extra: ucopy
    float* ucopy = (float*)(((uintptr_t)after_common + 15) & ~(uintptr_t)15);

    bool fast = (BN == 2LL * NODE_N) && (nEdges % EDGES_PER_BLOCK == 0) &&
                (ws_size >= need_fast);

    if (fast) {
        hipMemsetAsync(binCnt, 0, NBINS * sizeof(int), stream);
        int gridS = (int)(nEdges / EDGES_PER_BLOCK);     // 3072
        k_sortscatter<<<gridS, S_THREADS, 0, stream>>>(G, w, mask, nbr, u, binCnt, pairs);
        k_binaccum<<<NBINS, 1024, 0, stream>>>(binCnt, pairs, u);
    } else {
        hipMemsetAsync(ucopy, 0, (size_t)NXCD * BN * sizeof(float), stream);
        int edgeBlocks = (int)((nEdges + BLK - 1) / BLK);
        k_init_fb<<<nodeBlocks, BLK, 0, stream>>>(G, w, mask, u, BN);
        k_scatter_fb<<<edgeBlocks, BLK, 0, stream>>>(G, w, mask, nbr, ucopy, NODE_N, BN);
        k_usum_fb<<<nodeBlocks, BLK, 0, stream>>>(ucopy, u, BN);
    }
    k_v<<<nodeBlocks, BLK, 0, stream>>>(G, w, mask, nbr, u, v, BN);
    k_y<<<nodeBlocks, BLK, 0, stream>>>(Ad, Ao, w, mask, nbr, v, py, nodeBlocks, BN);
    k_final<<<1, 1024, 0, stream>>>(py, nodeBlocks, (float*)d_out);
}